// Round 10
// baseline (212.677 us; speedup 1.0000x reference)
//
#include <hip/hip_runtime.h>

#define NPTS    2000000
#define PIL     100000
#define BN_EPS_F 1e-3f

// counting-sort params
#define SHIFT   4
#define PPB     16                  // pillars per bucket
#define NBKT    6250                // PIL / PPB (exact)
#define NBAC    256                 // blocks for hist/scatter passes
#define CHUNK   7813                // ceil(NPTS / NBAC)
#define CAP     512                 // max records staged in LDS per bucket (mean 320 + 10.7 sd)

// d_ws float-index offsets (ws proven ~1 GB by harness 1.024e9-byte poison fills)
#define ACC_OFF    0                // 65 f
#define WP_OFF     128              // 320 f
#define BP_OFF     512              // 32 f
#define PART_OFF   1024             // 65*NBAC f (end 17,664)
#define TOTS_OFF   17920            // NBKT u32 (end 24,170)
#define STARTS_OFF 24576            // NBKT+1 u32 (end 30,827)
#define HIST_OFF   32768            // NBAC*NBKT u32 = 1,600,000 (end 1,632,768)
#define PS_OFF     1638400          // NPTS*12 f = 96 MB (total ~102.6 MB)

__device__ __forceinline__ constexpr int tri_idx(int j, int k) {
    return j * 10 - j * (j - 1) / 2 + (k - j);
}

// ---------------- kA: bucket histogram only (reads unq, 8 MB) ----------------
__global__ __launch_bounds__(512) void kA_hist(const int* __restrict__ unq,
                                               unsigned* __restrict__ hist)
{
    __shared__ unsigned h[NBKT];
    for (int i = threadIdx.x; i < NBKT; i += 512) h[i] = 0u;
    __syncthreads();
    const int lo = blockIdx.x * CHUNK;
    const int hi = min(lo + CHUNK, NPTS);
    for (int t = lo + threadIdx.x; t < hi; t += 512)
        atomicAdd(&h[unq[t] >> SHIFT], 1u);
    __syncthreads();
    for (int i = threadIdx.x; i < NBKT; i += 512)
        hist[(size_t)blockIdx.x * NBKT + i] = h[i];
}

// ---------------- kB1: per-bucket totals ----------------
__global__ __launch_bounds__(64) void kB1_colsum(const unsigned* __restrict__ hist,
                                                 unsigned* __restrict__ tots)
{
    const int c = blockIdx.x, lane = threadIdx.x;
    unsigned s = 0;
#pragma unroll
    for (int i = 0; i < NBAC / 64; ++i) s += hist[(size_t)(i * 64 + lane) * NBKT + c];
#pragma unroll
    for (int sh = 1; sh < 64; sh <<= 1) s += __shfl_xor(s, sh, 64);
    if (lane == 0) tots[c] = s;
}

// ---------------- kB2: scan totals (6250) -> bucket starts; 8 elems/thread ----------------
__global__ __launch_bounds__(1024) void kB2_scan(const unsigned* __restrict__ tots,
                                                 unsigned* __restrict__ starts)
{
    __shared__ unsigned ps[1024];
    const int t = threadIdx.x;
    unsigned v[8], sum = 0;
#pragma unroll
    for (int i = 0; i < 8; ++i) {
        int idx = t * 8 + i;
        v[i] = (idx < NBKT) ? tots[idx] : 0u;
        sum += v[i];
    }
    ps[t] = sum;
    __syncthreads();
    for (int d = 1; d < 1024; d <<= 1) {
        unsigned x = (t >= d) ? ps[t - d] : 0u;
        __syncthreads();
        ps[t] += x;
        __syncthreads();
    }
    unsigned excl = ps[t] - sum;
#pragma unroll
    for (int i = 0; i < 8; ++i) {
        int idx = t * 8 + i;
        if (idx < NBKT) starts[idx] = excl;
        excl += v[i];
    }
    if (t == 1023) starts[NBKT] = ps[1023];
}

// ---------------- kB3: expand per-(block,bucket) offsets IN PLACE over hist ----------------
__global__ __launch_bounds__(64) void kB3_expand(unsigned* __restrict__ hist,
                                                 const unsigned* __restrict__ starts)
{
    const int c = blockIdx.x, lane = threadIdx.x;
    unsigned hv[NBAC / 64];
    unsigned psum = 0;
#pragma unroll
    for (int i = 0; i < NBAC / 64; ++i) {
        hv[i] = hist[(size_t)(lane * (NBAC / 64) + i) * NBKT + c];
        psum += hv[i];
    }
    unsigned incl = psum;
#pragma unroll
    for (int s = 1; s < 64; s <<= 1) {
        unsigned v = __shfl_up(incl, s, 64);
        if (lane >= s) incl += v;
    }
    unsigned run = starts[c] + (incl - psum);
#pragma unroll
    for (int i = 0; i < NBAC / 64; ++i) {
        hist[(size_t)(lane * (NBAC / 64) + i) * NBKT + c] = run;
        run += hv[i];
    }
}

// ---------------- kC2: scatter 48B records into bucket order + ALL 65 moments ----------------
__global__ __launch_bounds__(512) void kC2_scatter_mom(const float* __restrict__ in,
                                                       const int* __restrict__ unq,
                                                       const unsigned* __restrict__ off,
                                                       float4* __restrict__ ps4,
                                                       float* __restrict__ partial)
{
    __shared__ unsigned cur[NBKT];
    __shared__ float lds2[8][66];
    for (int i = threadIdx.x; i < NBKT; i += 512)
        cur[i] = off[(size_t)blockIdx.x * NBKT + i];
    __syncthreads();

    float acc[65];
#pragma unroll
    for (int i = 0; i < 65; ++i) acc[i] = 0.f;

    const int lo = blockIdx.x * CHUNK;
    const int hi = min(lo + CHUNK, NPTS);
    for (int t = lo + threadIdx.x; t < hi; t += 512) {
        int pil = unq[t];
        unsigned slot = atomicAdd(&cur[pil >> SHIFT], 1u);
        const float* px = in + (size_t)t * 10;
        float4 r0 = *reinterpret_cast<const float4*>(px);
        float4 r1 = *reinterpret_cast<const float4*>(px + 4);
        float2 r2 = *reinterpret_cast<const float2*>(px + 8);
        unsigned meta = ((unsigned)(pil & (PPB - 1)) << 21) | (unsigned)t;
        float4* d = ps4 + (size_t)slot * 3;
        d[0] = r0;
        d[1] = r1;
        d[2] = make_float4(r2.x, r2.y, __uint_as_float(meta), 0.f);

        float xf[10] = { r0.x, r0.y, r0.z, r0.w, r1.x, r1.y, r1.z, r1.w, r2.x, r2.y };
#pragma unroll
        for (int j = 0; j < 10; ++j) acc[j] += xf[j];
        int o = 10;
#pragma unroll
        for (int j = 0; j < 10; ++j)
#pragma unroll
            for (int k = j; k < 10; ++k) acc[o++] += xf[j] * xf[k];
    }

#pragma unroll
    for (int i = 0; i < 65; ++i) {
        float v = acc[i];
#pragma unroll
        for (int s = 1; s < 64; s <<= 1) v += __shfl_xor(v, s, 64);
        acc[i] = v;
    }
    const int wid = threadIdx.x >> 6, lane = threadIdx.x & 63;
    if (lane == 0) {
#pragma unroll
        for (int i = 0; i < 65; ++i) lds2[wid][i] = acc[i];
    }
    __syncthreads();
    if (threadIdx.x < 65) {
        float s = 0.f;
#pragma unroll
        for (int wv = 0; wv < 8; ++wv) s += lds2[wv][threadIdx.x];
        partial[(size_t)threadIdx.x * NBAC + blockIdx.x] = s;
    }
}

// ---------------- k1f: reduce partials -> accum[65] ----------------
__global__ void k1_final(const float* __restrict__ partial, float* __restrict__ accum)
{
    const int e = blockIdx.x, lane = threadIdx.x;
    float s = 0.f;
#pragma unroll
    for (int i = 0; i < NBAC / 64; ++i) s += partial[(size_t)e * NBAC + i * 64 + lane];
#pragma unroll
    for (int sh = 1; sh < 64; sh <<= 1) s += __shfl_xor(s, sh, 64);
    if (lane == 0) accum[e] = s;
}

// ---------------- k2: finalize BN -> folded W', b' ----------------
__global__ void k2_finalize(const float* __restrict__ accum, const float* __restrict__ W,
                            const float* __restrict__ b, const float* __restrict__ gamma,
                            const float* __restrict__ beta, float* __restrict__ Wp,
                            float* __restrict__ bp)
{
    int c = threadIdx.x;
    if (c >= 32) return;
    const float invN = 1.0f / (float)NPTS;
    float m[10], w[10];
#pragma unroll
    for (int k = 0; k < 10; ++k) m[k] = accum[k] * invN;
#pragma unroll
    for (int k = 0; k < 10; ++k) w[k] = W[c*10 + k];
    float mean = b[c];
#pragma unroll
    for (int k = 0; k < 10; ++k) mean += w[k] * m[k];
    float var = 0.f;
#pragma unroll
    for (int j = 0; j < 10; ++j) {
#pragma unroll
        for (int k = j; k < 10; ++k) {
            float Cjk = accum[10 + tri_idx(j, k)] * invN - m[j] * m[k];
            var += w[j] * w[k] * Cjk * ((j == k) ? 1.f : 2.f);
        }
    }
    float scale = gamma[c] * rsqrtf(var + BN_EPS_F);
#pragma unroll
    for (int k = 0; k < 10; ++k) Wp[c*10 + k] = w[k] * scale;
    bp[c] = (b[c] - mean) * scale + beta[c];
}

// ---------------- kD8: whole-bucket LDS stage, 2 barriers, fused output ----------------
__device__ __forceinline__ float kd_affine(const float4& v0, const float4& v1,
                                           const float4& v2, const float* w, float bc)
{
    float a = bc;
    a += v0.x * w[0]; a += v0.y * w[1]; a += v0.z * w[2]; a += v0.w * w[3];
    a += v1.x * w[4]; a += v1.y * w[5]; a += v1.z * w[6]; a += v1.w * w[7];
    a += v2.x * w[8]; a += v2.y * w[9];
    return fmaxf(a, 0.f);
}

__global__ __launch_bounds__(256) void kD8_reduce(const float4* __restrict__ ps4,
                                                  const unsigned* __restrict__ starts,
                                                  const float* __restrict__ Wp,
                                                  const float* __restrict__ bp,
                                                  float* __restrict__ out)
{
    __shared__ unsigned tab[PPB * 32];   // 2 KB; tab[pl*32+c] -> bank c
    __shared__ float4 sbuf4[CAP * 3];    // 24 KB record stage
    for (int i = threadIdx.x; i < PPB * 32; i += 256) tab[i] = 0u;

    const int c   = threadIdx.x & 31;
    const int sub = threadIdx.x >> 5;    // 0..7
    float w[10];
#pragma unroll
    for (int k = 0; k < 10; ++k) w[k] = Wp[c * 10 + k];
    const float bc = bp[c];

    const unsigned s0 = starts[blockIdx.x];
    const unsigned s1 = starts[blockIdx.x + 1];
    const unsigned nrec = s1 - s0;
    const unsigned nlds = nrec < CAP ? nrec : CAP;

    // ---- stage bucket (nlds*3 float4s) with 4 loads in flight per batch ----
    const float4* g4 = ps4 + (size_t)s0 * 3;
    const unsigned n4 = nlds * 3;        // <= 1536
    for (unsigned base = 0; base < n4; base += 1024) {
        float4 v[4];
#pragma unroll
        for (int u = 0; u < 4; ++u) {
            unsigned j = base + u * 256 + threadIdx.x;
            if (j < n4) v[u] = g4[j];
        }
#pragma unroll
        for (int u = 0; u < 4; ++u) {
            unsigned j = base + u * 256 + threadIdx.x;
            if (j < n4) sbuf4[j] = v[u];
        }
    }
    __syncthreads();                      // tab zeroed + bucket staged

    // ---- phase 1: max into LDS table ----
    for (unsigned r = sub; r < nlds; r += 8) {
        float4 v0 = sbuf4[r*3], v1 = sbuf4[r*3+1], v2 = sbuf4[r*3+2];
        unsigned meta = __float_as_uint(v2.z);
        unsigned pl = (meta >> 21) & (PPB - 1);
        float a = kd_affine(v0, v1, v2, w, bc);
        atomicMax(&tab[(pl << 5) + c], __float_as_uint(a));
    }
    for (unsigned p = s0 + CAP + sub; p < s1; p += 8) {   // rare overflow
        const float4* rec = ps4 + (size_t)p * 3;
        float4 v0 = rec[0], v1 = rec[1], v2 = rec[2];
        unsigned meta = __float_as_uint(v2.z);
        unsigned pl = (meta >> 21) & (PPB - 1);
        float a = kd_affine(v0, v1, v2, w, bc);
        atomicMax(&tab[(pl << 5) + c], __float_as_uint(a));
    }
    __syncthreads();                      // table finished

    // ---- phase 2: recompute from LDS, combine, nontemporal coalesced store ----
    for (unsigned r = sub; r < nlds; r += 8) {
        float4 v0 = sbuf4[r*3], v1 = sbuf4[r*3+1], v2 = sbuf4[r*3+2];
        unsigned meta = __float_as_uint(v2.z);
        unsigned idx = meta & 0x1FFFFFu;
        unsigned pl = (meta >> 21) & (PPB - 1);
        float a = kd_affine(v0, v1, v2, w, bc);
        float mx = __uint_as_float(tab[(pl << 5) + c]);
        __builtin_nontemporal_store((a + mx) * 0.5f, &out[(size_t)idx * 32 + c]);
    }
    for (unsigned p = s0 + CAP + sub; p < s1; p += 8) {   // rare overflow
        const float4* rec = ps4 + (size_t)p * 3;
        float4 v0 = rec[0], v1 = rec[1], v2 = rec[2];
        unsigned meta = __float_as_uint(v2.z);
        unsigned idx = meta & 0x1FFFFFu;
        unsigned pl = (meta >> 21) & (PPB - 1);
        float a = kd_affine(v0, v1, v2, w, bc);
        float mx = __uint_as_float(tab[(pl << 5) + c]);
        __builtin_nontemporal_store((a + mx) * 0.5f, &out[(size_t)idx * 32 + c]);
    }
}

extern "C" void kernel_launch(void* const* d_in, const int* in_sizes, int n_in,
                              void* d_out, int out_size, void* d_ws, size_t ws_size,
                              hipStream_t stream)
{
    const float* in    = (const float*)d_in[0];
    const float* W     = (const float*)d_in[1];
    const float* b     = (const float*)d_in[2];
    const float* gamma = (const float*)d_in[3];
    const float* beta  = (const float*)d_in[4];
    const int*   unq   = (const int*)d_in[5];

    float* ws      = (float*)d_ws;
    float* accum   = ws + ACC_OFF;
    float* Wp      = ws + WP_OFF;
    float* bp      = ws + BP_OFF;
    float* partial = ws + PART_OFF;
    unsigned* tots   = (unsigned*)(ws + TOTS_OFF);
    unsigned* starts = (unsigned*)(ws + STARTS_OFF);
    unsigned* hist   = (unsigned*)(ws + HIST_OFF);   // becomes offsets after kB3
    float4*   ps4    = (float4*)(ws + PS_OFF);

    // bucket histogram (unq only) -> offsets
    kA_hist<<<NBAC, 512, 0, stream>>>(unq, hist);
    kB1_colsum<<<NBKT, 64, 0, stream>>>(hist, tots);
    kB2_scan<<<1, 1024, 0, stream>>>(tots, starts);
    kB3_expand<<<NBKT, 64, 0, stream>>>(hist, starts);
    // sort full records + accumulate all 65 input moments in the same pass
    kC2_scatter_mom<<<NBAC, 512, 0, stream>>>(in, unq, hist, ps4, partial);
    // BN fold
    k1_final<<<65, 64, 0, stream>>>(partial, accum);
    k2_finalize<<<1, 64, 0, stream>>>(accum, W, b, gamma, beta, Wp, bp);
    // per-bucket whole-bucket-staged LDS segment-max + fused output
    kD8_reduce<<<NBKT, 256, 0, stream>>>(ps4, starts, Wp, bp, (float*)d_out);
}